// Round 11
// baseline (1888.896 us; speedup 1.0000x reference)
//
#include <hip/hip_runtime.h>
#include <hip/hip_fp16.h>

#define Bsz 128
#define Tsz 512
#define Hsz 1024
#define MS  128
#define NT  512
#define NEL 4          // batch elements per block
#define NBLK (Bsz / NEL)
#define NPAIR 36

typedef __attribute__((ext_vector_type(2))) _Float16 h2_t;
union U32H2 { unsigned u; h2_t h; __half2 hh; };

__device__ __forceinline__ float fdot2u(unsigned w, unsigned h, float acc) {
#if __has_builtin(__builtin_amdgcn_fdot2)
    U32H2 a, b; a.u = w; b.u = h;
    return __builtin_amdgcn_fdot2(a.h, b.h, acc, false);
#else
    U32H2 a, b; a.u = w; b.u = h;
    float2 fa = __half22float2(a.hh), fb = __half22float2(b.hh);
    return acc + fa.x * fb.x + fa.y * fb.y;
#endif
}
__device__ __forceinline__ unsigned packh2(float a, float b) {
    U32H2 u; u.hh = __floats2half2_rn(a, b); return u.u;
}
__device__ __forceinline__ float2 unpackh2(unsigned d) {
    U32H2 u; u.u = d; return __half22float2(u.hh);
}
__device__ __forceinline__ float fast_tanh(float x) {
    const float e = __expf(2.0f * x);
    return 1.0f - 2.0f * __builtin_amdgcn_rcpf(e + 1.0f);
}

// ---------------------------------------------------------------------------
// Retile W_hh block (r,c) [tri p=c(c+1)/2+r] into packed-fp16 j-pair dwords:
//   WPp[p*8192 + jd*128 + row] = pack(W[r*128+row][c*128+2jd], [..2jd+1])
// ---------------------------------------------------------------------------
__global__ __launch_bounds__(256)
void retile(const float* __restrict__ W, unsigned* __restrict__ WPp) {
    __shared__ unsigned tile[64][132];
    const int p = blockIdx.x;
    int c = 0; while ((c + 1) * (c + 2) / 2 <= p) ++c;
    const int r = p - c * (c + 1) / 2;
    for (int i = threadIdx.x; i < 8192; i += 256) {
        const int row = i >> 6, jd = i & 63;
        const float* s = W + (size_t)(r * MS + row) * Hsz + c * MS + 2 * jd;
        tile[jd][row] = packh2(s[0], s[1]);
    }
    __syncthreads();
    unsigned* dst = WPp + (size_t)p * 8192;
    for (int i = threadIdx.x; i < 8192; i += 256) {
        const int jd = i >> 7, row = i & 127;
        dst[i] = tile[jd][row];
    }
}

// ---------------------------------------------------------------------------
// Multi-element Clockwork RNN: grid=32 blocks, 4 batch elements each,
// 512 threads (8 waves), 2 barriers/step (R7 skeleton).
// All weights packed fp16 (fdot2, fp32 accumulate); Sp partials fp16;
// h packed fp16 pairs. Weight loads (regs for pair0, L2 streams for rest)
// are shared across the 4 elements -> 4x reuse + 4-way ILP in every chain.
// ---------------------------------------------------------------------------
__global__ __launch_bounds__(NT)
void cwrnn_kernel(const float* __restrict__ x,      // [B, T+1, 2, 1]
                  const float* __restrict__ W_ih,   // [H, 2]
                  const float* __restrict__ fc_w,   // [2, H]
                  const float* __restrict__ fc_b,   // [2]
                  const float* __restrict__ enc_w,  // [H, 2]
                  const unsigned* __restrict__ WPp, // packed fp16 blocks
                  float* __restrict__ out)          // [B, T, 2]
{
    __shared__ __align__(16) unsigned short SpH[NPAIR - 1][NEL][2][MS]; // 71.7 KB
    __shared__ float  Sp00[NEL][MS];        // 2 KB
    __shared__ unsigned hp[NEL][Hsz / 2];   // 8 KB packed fp16 h
    __shared__ float2 x_s[NEL][Tsz + 1];    // 16.4 KB
    __shared__ float2 wih_s[Hsz];           // 8 KB
    __shared__ unsigned f0p[Hsz / 2], f1p[Hsz / 2];  // 4 KB
    __shared__ float  out_s[NEL][Tsz * 2];  // 16 KB
    __shared__ float2 ored[NEL][8];

    const int tid  = threadIdx.x;
    const int lane = tid & 63;
    const int wave = tid >> 6;
    const int b0   = blockIdx.x * NEL;

    // ---- preloads ----
    for (int i = tid; i < Hsz; i += NT) wih_s[i] = ((const float2*)W_ih)[i];
    for (int i = tid; i < Hsz / 2; i += NT) {
        f0p[i] = packh2(fc_w[2 * i],       fc_w[2 * i + 1]);
        f1p[i] = packh2(fc_w[Hsz + 2 * i], fc_w[Hsz + 2 * i + 1]);
    }
    #pragma unroll
    for (int e = 0; e < NEL; ++e) {
        const float2* xb = (const float2*)(x + (size_t)(b0 + e) * (Tsz + 1) * 2);
        for (int i = tid; i < Tsz + 1; i += NT) x_s[e][i] = xb[i];
        const float2 x0 = xb[0];
        for (int i = tid; i < Hsz / 2; i += NT) {
            const float2 eA = ((const float2*)enc_w)[2 * i];
            const float2 eB = ((const float2*)enc_w)[2 * i + 1];
            hp[e][i] = packh2(x0.x * eA.x + x0.y * eA.y,
                              x0.x * eB.x + x0.y * eB.y);
        }
    }
    const float fb0 = fc_b[0], fb1 = fc_b[1];

    // ---- pair-0 register cache (packed fp16): row00 = tid>>2, jd range jc*16..+15
    const int row00 = tid >> 2;
    const int jc    = tid & 3;
    unsigned w00[16];
    #pragma unroll
    for (int q = 0; q < 16; ++q)
        w00[q] = WPp[(jc * 16 + q) * MS + row00];

    // ---- streamed-pair mapping (R7's coalesced one) ----
    const int slot = tid >> 7;            // 0..3
    const int s    = tid & 127;
    const int row4 = (s & 31) * 4;
    const int jq   = s >> 5;              // 0..3
    const int part = s >> 6;              // 0 (jq 0,1) / 1 (jq 2,3)
    __syncthreads();

    auto refresh00 = [&]() {
        #pragma unroll
        for (int e = 0; e < NEL; ++e) {
            const unsigned* hb = &hp[e][jc * 16];
            float a = 0.f;
            #pragma unroll
            for (int q = 0; q < 4; ++q) {
                const uint4 h4 = *(const uint4*)(hb + 4 * q);
                a = fdot2u(w00[4*q+0], h4.x, a);
                a = fdot2u(w00[4*q+1], h4.y, a);
                a = fdot2u(w00[4*q+2], h4.z, a);
                a = fdot2u(w00[4*q+3], h4.w, a);
            }
            a += __shfl_xor(a, 1, 64);
            a += __shfl_xor(a, 2, 64);
            if (jc == 0) Sp00[e][row00] = a;
        }
    };

    auto do_pair = [&](int p, int c) {
        const unsigned* wp = WPp + (size_t)p * 8192 + jq * 16 * MS + row4;
        float4 acc[NEL];
        #pragma unroll
        for (int e = 0; e < NEL; ++e) acc[e] = make_float4(0.f, 0.f, 0.f, 0.f);
        #pragma unroll 4
        for (int jj = 0; jj < 16; ++jj) {
            const uint4 w4 = *(const uint4*)(wp + jj * MS);
            const int hidx = c * 64 + jq * 16 + jj;
            #pragma unroll
            for (int e = 0; e < NEL; ++e) {
                const unsigned hd = hp[e][hidx];
                acc[e].x = fdot2u(w4.x, hd, acc[e].x);
                acc[e].y = fdot2u(w4.y, hd, acc[e].y);
                acc[e].z = fdot2u(w4.z, hd, acc[e].z);
                acc[e].w = fdot2u(w4.w, hd, acc[e].w);
            }
        }
        #pragma unroll
        for (int e = 0; e < NEL; ++e) {
            acc[e].x += __shfl_xor(acc[e].x, 32, 64);
            acc[e].y += __shfl_xor(acc[e].y, 32, 64);
            acc[e].z += __shfl_xor(acc[e].z, 32, 64);
            acc[e].w += __shfl_xor(acc[e].w, 32, 64);
        }
        if ((s & 32) == 0) {
            #pragma unroll
            for (int e = 0; e < NEL; ++e) {
                U32H2 lo, hi;
                lo.hh = __floats2half2_rn(acc[e].x, acc[e].y);
                hi.hh = __floats2half2_rn(acc[e].z, acc[e].w);
                uint2 v; v.x = lo.u; v.y = hi.u;
                *(uint2*)&SpH[p - 1][e][part][row4] = v;
            }
        }
    };

    auto refresh_hi = [&](int P) {        // pairs 1..P-1, 4 slots concurrent
        for (int pb = 1; pb < P; pb += 4) {
            const int p = pb + slot;
            if (p < P) {
                int c = 1; while ((c + 1) * (c + 2) / 2 <= p) ++c;
                do_pair(p, c);
            }
        }
    };

    refresh_hi(NPAIR);
    refresh00();
    __syncthreads();

    for (int t = 0; t < Tsz; ++t) {
        const int A = (t == 0) ? 7 : min(__ffs(t) - 1, 7);
        const int nrows = (A + 1) * MS;
        const int e1 = tid >> 7;          // element for P1
        const int s2 = tid & 127;

        // ---- P1: candidate + h update (2 rows/thread/element-group) ----
        for (int rb = 0; rb < nrows; rb += 256) {
            const int row2 = rb + 2 * s2;
            if (row2 < nrows) {
                const int r  = row2 >> 7;
                const int il = row2 & (MS - 1);
                const float2 xt = x_s[e1][t + 1];
                const float2 wA = wih_s[row2], wB = wih_s[row2 + 1];
                float pre0 = xt.x * wA.x + xt.y * wA.y;
                float pre1 = xt.x * wB.x + xt.y * wB.y;
                if (r == 0) {
                    const float2 v = *(const float2*)&Sp00[e1][il];
                    pre0 += v.x; pre1 += v.y;
                }
                for (int c = (r == 0) ? 1 : r; c < 8; ++c) {
                    const int p = c * (c + 1) / 2 + r;
                    const unsigned d0 = *(const unsigned*)&SpH[p - 1][e1][0][il];
                    const unsigned d1 = *(const unsigned*)&SpH[p - 1][e1][1][il];
                    const float2 f0 = unpackh2(d0), f1 = unpackh2(d1);
                    pre0 += f0.x + f1.x;
                    pre1 += f0.y + f1.y;
                }
                hp[e1][row2 >> 1] = packh2(fast_tanh(pre0), fast_tanh(pre1));
            }
        }
        __syncthreads();                  // barrier 1

        // ---- refresh: streamed pairs first (VMEM early), then pair 0 ----
        refresh_hi((A + 1) * (A + 2) / 2);
        refresh00();

        // ---- P2: wave w owns module w; stale ored stays correct ----
        if (wave <= A) {
            float o0[NEL], o1[NEL];
            #pragma unroll
            for (int e = 0; e < NEL; ++e) {
                const unsigned hd = hp[e][wave * 64 + lane];
                o0[e] = fdot2u(hd, f0p[wave * 64 + lane], 0.f);
                o1[e] = fdot2u(hd, f1p[wave * 64 + lane], 0.f);
            }
            #pragma unroll
            for (int o = 1; o < 64; o <<= 1) {
                #pragma unroll
                for (int e = 0; e < NEL; ++e) {
                    o0[e] += __shfl_xor(o0[e], o, 64);
                    o1[e] += __shfl_xor(o1[e], o, 64);
                }
            }
            if (lane == 0) {
                #pragma unroll
                for (int e = 0; e < NEL; ++e)
                    ored[e][wave] = make_float2(o0[e], o1[e]);
            }
        }
        __syncthreads();                  // barrier 2

        // ---- P4: lanes 0..3 of wave 0 fold their element (overlaps next P1)
        if (tid < NEL) {
            float o0 = fb0, o1 = fb1;
            #pragma unroll
            for (int m = 0; m < 8; ++m) {
                o0 += ored[tid][m].x;
                o1 += ored[tid][m].y;
            }
            out_s[tid][2 * t]     = o0;
            out_s[tid][2 * t + 1] = o1;
        }
        // ored WAR: next P2 write happens after next barrier 1, which wave 0
        // (owner of P4 lanes) must also pass. Safe.
    }

    __syncthreads();
    #pragma unroll
    for (int e = 0; e < NEL; ++e) {
        float* outb = out + (size_t)(b0 + e) * Tsz * 2;
        for (int i = tid; i < Tsz * 2; i += NT) outb[i] = out_s[e][i];
    }
}

// ---------------------------------------------------------------------------
extern "C" void kernel_launch(void* const* d_in, const int* in_sizes, int n_in,
                              void* d_out, int out_size, void* d_ws, size_t ws_size,
                              hipStream_t stream) {
    const float* x     = (const float*)d_in[0];
    const float* W_ih  = (const float*)d_in[1];
    const float* W_hh  = (const float*)d_in[2];
    const float* fc_w  = (const float*)d_in[3];
    const float* fc_b  = (const float*)d_in[4];
    const float* enc_w = (const float*)d_in[5];
    float* outp = (float*)d_out;
    unsigned* WPp = (unsigned*)d_ws;      // 36*8192*4 = 1.18 MB

    retile<<<NPAIR, 256, 0, stream>>>(W_hh, WPp);
    cwrnn_kernel<<<NBLK, NT, 0, stream>>>(x, W_ih, fc_w, fc_b, enc_w, WPp, outp);
}